// Round 1
// 1092.908 us; speedup vs baseline: 1.9011x; 1.9011x over previous
//
#include <hip/hip_runtime.h>
#include <math.h>

// MHA forward, MI355X/gfx950. B=2, S=2048, D=1024, H=16, DH=64.
// Outputs: out [2,2048,1024] fp32, then weights [2,16,2048,2048] fp32.
//
// Strategy (this round): all GEMMs on bf16 MFMA (mfma_f32_16x16x32_bf16),
// m97-style structure: NT layout (B pre-transposed), LDS staging via
// global_load_lds width=16, single-buffered 2-barrier K-loop.
// fp32 softmax kept; AV GEMM converts fp32 P -> bf16 during LDS staging.

typedef unsigned short u16;
typedef __attribute__((ext_vector_type(8))) short bf16x8;
typedef __attribute__((ext_vector_type(4))) float f32x4;

__device__ __forceinline__ u16 f2bf(float f) {
  union { float f; unsigned u; } v;
  v.f = f;
  unsigned r = v.u + 0x7fffu + ((v.u >> 16) & 1u);  // RNE
  return (u16)(r >> 16);
}

#define GLD16(g, l)                                       \
  __builtin_amdgcn_global_load_lds(                       \
      (const __attribute__((address_space(1))) void*)(g), \
      (__attribute__((address_space(3))) void*)(l), 16, 0, 0)

// Stage a ROWS x 32 bf16 tile (global row stride ld) into LDS linear
// [ROWS][32]. One wave chunk = 16 rows = 1KB; dest must be linear in
// lane order (global_load_lds constraint), which matches row-major.
template <int ROWS>
__device__ __forceinline__ void stage_bf16(const u16* __restrict__ src, int ld,
                                           u16* dst, int wid, int lane) {
  constexpr int NCH = ROWS / 16;
#pragma unroll
  for (int c = wid; c < NCH; c += 4) {
    const u16* g = src + (size_t)(c * 16 + (lane >> 2)) * ld + (lane & 3) * 8;
    u16* l = dst + c * 512 + lane * 8;  // == base + lane*16B within chunk
    GLD16(g, l);
  }
}

// C[M,N] = alpha * A[M,K] @ B[N,K]^T (+bias). 256 thr = 4 waves, wave grid
// (BM/WM)x(BN/WN) must be 4. BK=32. A is bf16 (AF32=0) or fp32 converted
// during staging (AF32=1). Output fp32 or bf16 (OBF16).
// z -> (bb=z/hdiv, hh=z%hdiv), per-operand (bb,hh) strides in elements.
template <int BM, int BN, int WM, int WN, bool AF32, bool OBF16>
__global__ __launch_bounds__(256) void mm_nt(
    const void* __restrict__ A, const u16* __restrict__ B,
    const float* __restrict__ bias, void* __restrict__ C, int K, int lda,
    int ldb, int ldc, size_t sAb, size_t sAh, size_t sBb, size_t sBh,
    size_t sCb, size_t sCh, int hdiv, float alpha) {
  constexpr int WAVES_N = BN / WN;
  constexpr int MR = WM / 16, NR = WN / 16;
  static_assert((BM / WM) * (BN / WN) == 4, "4 waves");
  __shared__ u16 As[BM * 32];
  __shared__ u16 Bs[BN * 32];

  const int z = blockIdx.z;
  const int bb = z / hdiv, hh = z % hdiv;
  const int row0 = blockIdx.y * BM;
  const int col0 = blockIdx.x * BN;
  const int tid = threadIdx.x;
  const int lane = tid & 63, wid = tid >> 6;
  const int wm0 = (wid / WAVES_N) * WM;
  const int wn0 = (wid % WAVES_N) * WN;
  const int lw = lane & 15, lg = lane >> 4;

  const float* Afb = nullptr;
  const u16* Aub = nullptr;
  if constexpr (AF32)
    Afb = (const float*)A + (size_t)bb * sAb + (size_t)hh * sAh +
          (size_t)row0 * lda;
  else
    Aub = (const u16*)A + (size_t)bb * sAb + (size_t)hh * sAh +
          (size_t)row0 * lda;
  const u16* Bsrc =
      B + (size_t)bb * sBb + (size_t)hh * sBh + (size_t)col0 * ldb;

  f32x4 acc[MR][NR] = {};

  for (int k0 = 0; k0 < K; k0 += 32) {
    if constexpr (AF32) {
      // fp32 -> bf16 conversion staging (reg path), tile BM x 32
#pragma unroll
      for (int p = 0; p < BM / 32; ++p) {
        const int e = (p * 256 + tid) * 4;
        const int r = e >> 5, k = e & 31;
        const float4 v = *(const float4*)(Afb + (size_t)r * lda + (k0 + k));
        *(ushort4*)&As[r * 32 + k] =
            make_ushort4(f2bf(v.x), f2bf(v.y), f2bf(v.z), f2bf(v.w));
      }
    } else {
      stage_bf16<BM>(Aub + k0, lda, As, wid, lane);
    }
    stage_bf16<BN>(Bsrc + k0, ldb, Bs, wid, lane);
    __syncthreads();

    bf16x8 af[MR], bfr[NR];
#pragma unroll
    for (int mi = 0; mi < MR; ++mi)
      af[mi] = *(const bf16x8*)&As[(wm0 + mi * 16 + lw) * 32 + lg * 8];
#pragma unroll
    for (int nj = 0; nj < NR; ++nj)
      bfr[nj] = *(const bf16x8*)&Bs[(wn0 + nj * 16 + lw) * 32 + lg * 8];
#pragma unroll
    for (int mi = 0; mi < MR; ++mi)
#pragma unroll
      for (int nj = 0; nj < NR; ++nj)
        acc[mi][nj] = __builtin_amdgcn_mfma_f32_16x16x32_bf16(
            af[mi], bfr[nj], acc[mi][nj], 0, 0, 0);
    __syncthreads();
  }

  // Epilogue. C/D layout (HW-verified): col=lane&15, row=(lane>>4)*4+reg.
  float* Cf = nullptr;
  u16* Cu = nullptr;
  if constexpr (OBF16)
    Cu = (u16*)C + (size_t)bb * sCb + (size_t)hh * sCh;
  else
    Cf = (float*)C + (size_t)bb * sCb + (size_t)hh * sCh;
#pragma unroll
  for (int mi = 0; mi < MR; ++mi) {
#pragma unroll
    for (int nj = 0; nj < NR; ++nj) {
      const int c = col0 + wn0 + nj * 16 + lw;
      const float bv = bias ? bias[c] : 0.f;
#pragma unroll
      for (int q = 0; q < 4; ++q) {
        const int r = row0 + wm0 + mi * 16 + lg * 4 + q;
        const float v = alpha * acc[mi][nj][q] + bv;
        if constexpr (OBF16)
          Cu[(size_t)r * ldc + c] = f2bf(v);
        else
          Cf[(size_t)r * ldc + c] = v;
      }
    }
  }
}

// x fp32 -> bf16, elementwise (float4 -> ushort4)
__global__ __launch_bounds__(256) void cvt_x_kernel(
    const float* __restrict__ src, u16* __restrict__ dst, int n4) {
  int i = blockIdx.x * 256 + threadIdx.x;
  const int stride = gridDim.x * 256;
  for (; i < n4; i += stride) {
    const float4 v = ((const float4*)src)[i];
    ((ushort4*)dst)[i] = make_ushort4(f2bf(v.x), f2bf(v.y), f2bf(v.z), f2bf(v.w));
  }
}

// weight fp32 [1024][1024] -> bf16 transposed [1024][1024]
__global__ __launch_bounds__(256) void wtrans_kernel(
    const float* __restrict__ src, u16* __restrict__ dst) {
  __shared__ float t[32][33];
  const int tx = threadIdx.x % 32, ty = threadIdx.x / 32;
  const int r0 = blockIdx.y * 32, c0 = blockIdx.x * 32;
#pragma unroll
  for (int i = 0; i < 32; i += 8)
    t[ty + i][tx] = src[(size_t)(r0 + ty + i) * 1024 + c0 + tx];
  __syncthreads();
#pragma unroll
  for (int i = 0; i < 32; i += 8)
    dst[(size_t)(c0 + ty + i) * 1024 + r0 + tx] = f2bf(t[tx][ty + i]);
}

// V bf16 [2048][1024] -> Vt bf16 [1024][2048], per batch (z)
__global__ __launch_bounds__(256) void vtrans_kernel(
    const u16* __restrict__ src, u16* __restrict__ dst) {
  __shared__ u16 t[32][33];
  const size_t zo = (size_t)blockIdx.z * 2048 * 1024;
  const int tx = threadIdx.x % 32, ty = threadIdx.x / 32;
  const int r0 = blockIdx.y * 32, c0 = blockIdx.x * 32;  // r over 2048 rows
#pragma unroll
  for (int i = 0; i < 32; i += 8)
    t[ty + i][tx] = src[zo + (size_t)(r0 + ty + i) * 1024 + c0 + tx];
  __syncthreads();
#pragma unroll
  for (int i = 0; i < 32; i += 8)
    dst[zo + (size_t)(c0 + ty + i) * 2048 + r0 + tx] = t[tx][ty + i];
}

// In-place row softmax: one block (256 thr) per row of 2048. (unchanged)
__global__ __launch_bounds__(256) void softmax_kernel(float* __restrict__ w) {
  const size_t row = blockIdx.x;
  float* p = w + row * 2048;
  const int tid = threadIdx.x;
  const int wave = tid >> 6, lane = tid & 63;

  float v[8];
  float m = -1e30f;
#pragma unroll
  for (int i = 0; i < 8; i++) {
    v[i] = p[tid + i * 256];
    m = fmaxf(m, v[i]);
  }
#pragma unroll
  for (int off = 32; off > 0; off >>= 1) m = fmaxf(m, __shfl_xor(m, off, 64));
  __shared__ float redm[4];
  if (lane == 0) redm[wave] = m;
  __syncthreads();
  m = fmaxf(fmaxf(redm[0], redm[1]), fmaxf(redm[2], redm[3]));

  float s = 0.f;
#pragma unroll
  for (int i = 0; i < 8; i++) {
    v[i] = __expf(v[i] - m);
    s += v[i];
  }
#pragma unroll
  for (int off = 32; off > 0; off >>= 1) s += __shfl_xor(s, off, 64);
  __shared__ float reds[4];
  if (lane == 0) reds[wave] = s;
  __syncthreads();
  s = reds[0] + reds[1] + reds[2] + reds[3];

  const float inv = 1.0f / s;
#pragma unroll
  for (int i = 0; i < 8; i++) p[tid + i * 256] = v[i] * inv;
}

extern "C" void kernel_launch(void* const* d_in, const int* in_sizes, int n_in,
                              void* d_out, int out_size, void* d_ws,
                              size_t ws_size, hipStream_t stream) {
  const float* x = (const float*)d_in[0];
  const float* wq = (const float*)d_in[1];
  const float* bq = (const float*)d_in[2];
  const float* wk = (const float*)d_in[3];
  const float* bk = (const float*)d_in[4];
  const float* wv = (const float*)d_in[5];
  const float* bv = (const float*)d_in[6];
  const float* wo = (const float*)d_in[7];
  const float* bo = (const float*)d_in[8];

  const int Bz = 2, S = 2048, D = 1024, H = 16;
  const size_t MS = (size_t)Bz * S;  // 4096 rows

  float* out = (float*)d_out;             // [2,2048,1024]
  float* wts = out + MS * D;              // [2,16,2048,2048]

  // workspace: 56 MB of bf16 buffers
  u16* xb = (u16*)d_ws;        // [4096,1024]
  u16* wqt = xb + MS * D;      // [1024,1024] = wq^T
  u16* wkt = wqt + (size_t)D * D;
  u16* wvt = wkt + (size_t)D * D;
  u16* wot = wvt + (size_t)D * D;
  u16* Qb = wot + (size_t)D * D;   // [4096,1024]
  u16* Kb = Qb + MS * D;           // [4096,1024]
  u16* Vb = Kb + MS * D;           // [4096,1024]
  u16* Vt = Vb + MS * D;           // [2][1024,2048]
  u16* Attb = Vt + MS * D;         // [4096,1024]

  dim3 blk(256);

  // ---- dtype prep ----
  cvt_x_kernel<<<1024, blk, 0, stream>>>(x, xb, (int)(MS * D / 4));
  wtrans_kernel<<<dim3(32, 32), blk, 0, stream>>>(wq, wqt);
  wtrans_kernel<<<dim3(32, 32), blk, 0, stream>>>(wk, wkt);
  wtrans_kernel<<<dim3(32, 32), blk, 0, stream>>>(wv, wvt);
  wtrans_kernel<<<dim3(32, 32), blk, 0, stream>>>(wo, wot);

  // ---- Q/K/V projections: [4096,1024] = xb @ w^T + b -> bf16 ----
  dim3 gproj(D / 128, (int)(MS / 64), 1);  // 512 blocks
  mm_nt<64, 128, 32, 64, false, true><<<gproj, blk, 0, stream>>>(
      xb, wqt, bq, Qb, D, D, D, D, 0, 0, 0, 0, 0, 0, 1, 1.f);
  mm_nt<64, 128, 32, 64, false, true><<<gproj, blk, 0, stream>>>(
      xb, wkt, bk, Kb, D, D, D, D, 0, 0, 0, 0, 0, 0, 1, 1.f);
  mm_nt<64, 128, 32, 64, false, true><<<gproj, blk, 0, stream>>>(
      xb, wvt, bv, Vb, D, D, D, D, 0, 0, 0, 0, 0, 0, 1, 1.f);

  // ---- V^T per batch for the AV GEMM ----
  vtrans_kernel<<<dim3(32, 64, 2), blk, 0, stream>>>(Vb, Vt);

  // ---- scores = (Q_h @ K_h^T) * 1/8 -> wts fp32 (raw) ----
  dim3 gsc(S / 128, S / 128, Bz * H);  // 8192 blocks
  mm_nt<128, 128, 64, 64, false, false><<<gsc, blk, 0, stream>>>(
      Qb, Kb, nullptr, wts, 64, D, D, S, (size_t)S * D, 64, (size_t)S * D, 64,
      (size_t)H * S * S, (size_t)S * S, H, 0.125f);

  // ---- softmax rows in-place ----
  softmax_kernel<<<(int)(Bz * H * S), blk, 0, stream>>>(wts);

  // ---- attended_h = P_h (fp32->bf16 staged) @ V_h -> Attb bf16 ----
  dim3 gav(1, S / 64, Bz * H);  // 1024 blocks
  mm_nt<64, 64, 32, 32, true, true><<<gav, blk, 0, stream>>>(
      wts, Vt, nullptr, Attb, S, S, S, D, (size_t)H * S * S, (size_t)S * S,
      (size_t)D * S, (size_t)64 * S, (size_t)S * D, 64, H, 1.f);

  // ---- out = Attb @ wo^T + bo -> fp32 ----
  mm_nt<64, 128, 32, 64, false, false><<<gproj, blk, 0, stream>>>(
      Attb, wot, bo, out, D, D, D, D, 0, 0, 0, 0, 0, 0, 1, 1.f);
}

// Round 4
// 919.721 us; speedup vs baseline: 2.2591x; 1.1883x over previous
//
#include <hip/hip_runtime.h>
#include <math.h>

// MHA forward, MI355X/gfx950. B=2, S=2048, D=1024, H=16, DH=64.
// Outputs: out [2,2048,1024] fp32, then weights [2,16,2048,2048] fp32.
//
// Round 4: round-2 design with the fused scores+softmax kernel restructured
// to <64 KB LDS (K staged in 8 phases of 512 rows x 32 k), in case the two
// container failures were the 134 KB static-LDS allocation. Algorithm
// unchanged: weights written once, bf16 P copy for AV, fused QKV GEMM,
// all GEMMs on mfma_f32_16x16x32_bf16.

typedef unsigned short u16;
typedef __attribute__((ext_vector_type(8))) short bf16x8;
typedef __attribute__((ext_vector_type(4))) float f32x4;

__device__ __forceinline__ u16 f2bf(float f) {
  union { float f; unsigned u; } v;
  v.f = f;
  unsigned r = v.u + 0x7fffu + ((v.u >> 16) & 1u);  // RNE
  return (u16)(r >> 16);
}

#define GLD16(g, l)                                       \
  __builtin_amdgcn_global_load_lds(                       \
      (const __attribute__((address_space(1))) void*)(g), \
      (__attribute__((address_space(3))) void*)(l), 16, 0, 0)

// Stage ROWS x 32 bf16 tile (global row stride ld) into linear LDS
// [ROWS][32] via global_load_lds. NW = waves in block. One chunk = 16 rows.
template <int ROWS, int NW>
__device__ __forceinline__ void stage_g(const u16* __restrict__ src, int ld,
                                        u16* dst, int wid, int lane) {
  constexpr int NCH = ROWS / 16;
#pragma unroll
  for (int c = wid; c < NCH; c += NW) {
    const u16* g = src + (size_t)(c * 16 + (lane >> 2)) * ld + (lane & 3) * 8;
    u16* l = dst + c * 512 + lane * 8;
    GLD16(g, l);
  }
}

// C[M,N] = alpha * A[M,K] @ B[N,K]^T (+bias). 256 thr = 4 waves.
template <int BM, int BN, int WM, int WN, bool AF32, bool OBF16>
__global__ __launch_bounds__(256) void mm_nt(
    const void* __restrict__ A, const u16* __restrict__ B,
    const float* __restrict__ bias, void* __restrict__ C, int K, int lda,
    int ldb, int ldc, size_t sAb, size_t sAh, size_t sBb, size_t sBh,
    size_t sCb, size_t sCh, int hdiv, float alpha) {
  constexpr int WAVES_N = BN / WN;
  constexpr int MR = WM / 16, NR = WN / 16;
  static_assert((BM / WM) * (BN / WN) == 4, "4 waves");
  __shared__ u16 As[BM * 32];
  __shared__ u16 Bs[BN * 32];

  const int z = blockIdx.z;
  const int bb = z / hdiv, hh = z % hdiv;
  const int row0 = blockIdx.y * BM;
  const int col0 = blockIdx.x * BN;
  const int tid = threadIdx.x;
  const int lane = tid & 63, wid = tid >> 6;
  const int wm0 = (wid / WAVES_N) * WM;
  const int wn0 = (wid % WAVES_N) * WN;
  const int lw = lane & 15, lg = lane >> 4;

  const float* Afb = nullptr;
  const u16* Aub = nullptr;
  if constexpr (AF32)
    Afb = (const float*)A + (size_t)bb * sAb + (size_t)hh * sAh +
          (size_t)row0 * lda;
  else
    Aub = (const u16*)A + (size_t)bb * sAb + (size_t)hh * sAh +
          (size_t)row0 * lda;
  const u16* Bsrc =
      B + (size_t)bb * sBb + (size_t)hh * sBh + (size_t)col0 * ldb;

  f32x4 acc[MR][NR] = {};

  for (int k0 = 0; k0 < K; k0 += 32) {
    if constexpr (AF32) {
#pragma unroll
      for (int p = 0; p < BM / 32; ++p) {
        const int e = (p * 256 + tid) * 4;
        const int r = e >> 5, k = e & 31;
        const float4 v = *(const float4*)(Afb + (size_t)r * lda + (k0 + k));
        *(ushort4*)&As[r * 32 + k] =
            make_ushort4(f2bf(v.x), f2bf(v.y), f2bf(v.z), f2bf(v.w));
      }
    } else {
      stage_g<BM, 4>((const u16*)Aub + k0, lda, As, wid, lane);
    }
    stage_g<BN, 4>(Bsrc + k0, ldb, Bs, wid, lane);
    __syncthreads();

    bf16x8 af[MR], bfr[NR];
#pragma unroll
    for (int mi = 0; mi < MR; ++mi)
      af[mi] = *(const bf16x8*)&As[(wm0 + mi * 16 + lw) * 32 + lg * 8];
#pragma unroll
    for (int nj = 0; nj < NR; ++nj)
      bfr[nj] = *(const bf16x8*)&Bs[(wn0 + nj * 16 + lw) * 32 + lg * 8];
#pragma unroll
    for (int mi = 0; mi < MR; ++mi)
#pragma unroll
      for (int nj = 0; nj < NR; ++nj)
        acc[mi][nj] = __builtin_amdgcn_mfma_f32_16x16x32_bf16(
            af[mi], bfr[nj], acc[mi][nj], 0, 0, 0);
    __syncthreads();
  }

  float* Cf = nullptr;
  u16* Cu = nullptr;
  if constexpr (OBF16)
    Cu = (u16*)C + (size_t)bb * sCb + (size_t)hh * sCh;
  else
    Cf = (float*)C + (size_t)bb * sCb + (size_t)hh * sCh;
#pragma unroll
  for (int mi = 0; mi < MR; ++mi) {
#pragma unroll
    for (int nj = 0; nj < NR; ++nj) {
      const int c = col0 + wn0 + nj * 16 + lw;
      const float bv = bias ? bias[c] : 0.f;
#pragma unroll
      for (int q = 0; q < 4; ++q) {
        const int r = row0 + wm0 + mi * 16 + lg * 4 + q;
        const float v = alpha * acc[mi][nj][q] + bv;
        if constexpr (OBF16)
          Cu[(size_t)r * ldc + c] = f2bf(v);
        else
          Cf[(size_t)r * ldc + c] = v;
      }
    }
  }
}

// Fused scores + softmax. One 1024-thread block (16 waves) computes a full
// 32-row x 2048-col score block: S = (Q_h[32,64] @ K_h^T[64,2048]) / 8,
// softmax over the 2048 cols in registers, writes fp32 weights once
// (+ optional bf16 P). K staged in 8 phases of [512 rows][32 k] (32 KB).
// acc[mi][a]: row = mi*16 + lg*4 + q, col = (a>>1)*512 + wid*32 + (a&1)*16 + lw.
// QKV layout: [4096][3072] bf16 (Q | K | V), row = b*2048+s.
template <bool WRITE_P>
__global__ __launch_bounds__(1024) void score_softmax_kernel(
    const u16* __restrict__ QKV, float* __restrict__ W, u16* __restrict__ P) {
  __shared__ u16 Ks[512 * 32];      // 32 KB
  __shared__ u16 Qs[2][32 * 32];    // 4 KB
  __shared__ float red[2][32][16];  // 4 KB

  // XCD swizzle: 2048 blocks, 8 XCDs -> 256-block contiguous chunks/XCD.
  const int bid = blockIdx.x;
  const int swz = (bid & 7) * 256 + (bid >> 3);
  const int z = swz >> 6;   // 0..31 = (b,h)
  const int rb = swz & 63;  // row-block within head
  const int bb = z >> 4, hh = z & 15;
  const int row0 = rb * 32;

  const int tid = threadIdx.x;
  const int lane = tid & 63, wid = tid >> 6;
  const int lw = lane & 15, lg = lane >> 4;

  const u16* Qh = QKV + (size_t)bb * 2048 * 3072 + (size_t)hh * 64;
  const u16* Kh = Qh + 1024;

  f32x4 acc[2][8] = {};
  bf16x8 af[2][2];

#pragma unroll
  for (int ph = 0; ph < 8; ++ph) {
    const int qr = ph >> 1, kc2 = ph & 1;  // K-row quarter, k-chunk
    stage_g<512, 16>(Kh + (size_t)(qr * 512) * 3072 + kc2 * 32, 3072, Ks, wid,
                     lane);
    if (ph == 0) {
      stage_g<32, 16>(Qh + (size_t)row0 * 3072, 3072, Qs[0], wid, lane);
      stage_g<32, 16>(Qh + (size_t)row0 * 3072 + 32, 3072, Qs[1], wid, lane);
    }
    __syncthreads();
    if (ph == 0) {
#pragma unroll
      for (int kc = 0; kc < 2; ++kc)
#pragma unroll
        for (int mi = 0; mi < 2; ++mi)
          af[mi][kc] = *(const bf16x8*)&Qs[kc][(mi * 16 + lw) * 32 + lg * 8];
    }
#pragma unroll
    for (int nj = 0; nj < 2; ++nj) {
      const bf16x8 bf =
          *(const bf16x8*)&Ks[(wid * 32 + nj * 16 + lw) * 32 + lg * 8];
#pragma unroll
      for (int mi = 0; mi < 2; ++mi)
        acc[mi][qr * 2 + nj] = __builtin_amdgcn_mfma_f32_16x16x32_bf16(
            af[mi][kc2], bf, acc[mi][qr * 2 + nj], 0, 0, 0);
    }
    if (ph < 7) __syncthreads();
  }

  // ---- softmax in registers ----
  float rm[2][4], rs[2][4];
#pragma unroll
  for (int mi = 0; mi < 2; ++mi)
#pragma unroll
    for (int q = 0; q < 4; ++q) {
      float m = -1e30f;
#pragma unroll
      for (int a = 0; a < 8; ++a) {
        acc[mi][a][q] *= 0.125f;
        m = fmaxf(m, acc[mi][a][q]);
      }
#pragma unroll
      for (int off = 8; off >= 1; off >>= 1)
        m = fmaxf(m, __shfl_xor(m, off, 64));
      rm[mi][q] = m;
    }
  if (lw == 0) {
#pragma unroll
    for (int mi = 0; mi < 2; ++mi)
#pragma unroll
      for (int q = 0; q < 4; ++q)
        red[0][mi * 16 + lg * 4 + q][wid] = rm[mi][q];
  }
  __syncthreads();
#pragma unroll
  for (int mi = 0; mi < 2; ++mi)
#pragma unroll
    for (int q = 0; q < 4; ++q) {
      float m = -1e30f;
#pragma unroll
      for (int w = 0; w < 16; ++w)
        m = fmaxf(m, red[0][mi * 16 + lg * 4 + q][w]);
      rm[mi][q] = m;
    }

#pragma unroll
  for (int mi = 0; mi < 2; ++mi)
#pragma unroll
    for (int q = 0; q < 4; ++q) {
      float s = 0.f;
#pragma unroll
      for (int a = 0; a < 8; ++a) {
        const float e = __expf(acc[mi][a][q] - rm[mi][q]);
        acc[mi][a][q] = e;
        s += e;
      }
#pragma unroll
      for (int off = 8; off >= 1; off >>= 1) s += __shfl_xor(s, off, 64);
      rs[mi][q] = s;
    }
  if (lw == 0) {
#pragma unroll
    for (int mi = 0; mi < 2; ++mi)
#pragma unroll
      for (int q = 0; q < 4; ++q)
        red[1][mi * 16 + lg * 4 + q][wid] = rs[mi][q];
  }
  __syncthreads();
#pragma unroll
  for (int mi = 0; mi < 2; ++mi)
#pragma unroll
    for (int q = 0; q < 4; ++q) {
      float s = 0.f;
#pragma unroll
      for (int w = 0; w < 16; ++w) s += red[1][mi * 16 + lg * 4 + q][w];
      rs[mi][q] = 1.0f / s;
    }

  // ---- stores: fp32 weights (final) + optional bf16 P ----
  float* Wh = W + ((size_t)(bb * 16 + hh) * 2048 + row0) * 2048;
  u16* Ph = P + ((size_t)(bb * 16 + hh) * 2048 + row0) * 2048;
#pragma unroll
  for (int mi = 0; mi < 2; ++mi)
#pragma unroll
    for (int q = 0; q < 4; ++q) {
      const int r = mi * 16 + lg * 4 + q;
      const float inv = rs[mi][q];
#pragma unroll
      for (int a = 0; a < 8; ++a) {
        const int c = (a >> 1) * 512 + wid * 32 + (a & 1) * 16 + lw;
        const float v = acc[mi][a][q] * inv;
        Wh[(size_t)r * 2048 + c] = v;
        if constexpr (WRITE_P) Ph[(size_t)r * 2048 + c] = f2bf(v);
      }
    }
}

// x fp32 -> bf16, elementwise
__global__ __launch_bounds__(256) void cvt_x_kernel(
    const float* __restrict__ src, u16* __restrict__ dst, int n4) {
  int i = blockIdx.x * 256 + threadIdx.x;
  const int stride = gridDim.x * 256;
  for (; i < n4; i += stride) {
    const float4 v = ((const float4*)src)[i];
    ((ushort4*)dst)[i] =
        make_ushort4(f2bf(v.x), f2bf(v.y), f2bf(v.z), f2bf(v.w));
  }
}

// pack [bq|bk|bv] fp32 -> bqkv[3072] (graph-safe, no memcpy)
__global__ __launch_bounds__(1024) void pack_bias_kernel(
    const float* __restrict__ bq, const float* __restrict__ bk,
    const float* __restrict__ bv, float* __restrict__ dst) {
  const float* src = blockIdx.x == 0 ? bq : (blockIdx.x == 1 ? bk : bv);
  dst[blockIdx.x * 1024 + threadIdx.x] = src[threadIdx.x];
}

// weight fp32 [1024][1024] -> bf16 transposed [1024][1024]
__global__ __launch_bounds__(256) void wtrans_kernel(
    const float* __restrict__ src, u16* __restrict__ dst) {
  __shared__ float t[32][33];
  const int tx = threadIdx.x % 32, ty = threadIdx.x / 32;
  const int r0 = blockIdx.y * 32, c0 = blockIdx.x * 32;
#pragma unroll
  for (int i = 0; i < 32; i += 8)
    t[ty + i][tx] = src[(size_t)(r0 + ty + i) * 1024 + c0 + tx];
  __syncthreads();
#pragma unroll
  for (int i = 0; i < 32; i += 8)
    dst[(size_t)(c0 + ty + i) * 1024 + r0 + tx] = f2bf(t[tx][ty + i]);
}

// V bf16 [2048][ld] slice -> Vt bf16 [1024][2048], per batch (z)
__global__ __launch_bounds__(256) void vtrans_kernel(
    const u16* __restrict__ src, u16* __restrict__ dst, int ld) {
  __shared__ u16 t[32][33];
  const int tx = threadIdx.x % 32, ty = threadIdx.x / 32;
  const int r0 = blockIdx.y * 32, c0 = blockIdx.x * 32;
  const size_t so = (size_t)blockIdx.z * 2048 * ld;
  const size_t dz = (size_t)blockIdx.z * 1024 * 2048;
#pragma unroll
  for (int i = 0; i < 32; i += 8)
    t[ty + i][tx] = src[so + (size_t)(r0 + ty + i) * ld + c0 + tx];
  __syncthreads();
#pragma unroll
  for (int i = 0; i < 32; i += 8)
    dst[dz + (size_t)(c0 + ty + i) * 2048 + r0 + tx] = t[tx][ty + i];
}

extern "C" void kernel_launch(void* const* d_in, const int* in_sizes, int n_in,
                              void* d_out, int out_size, void* d_ws,
                              size_t ws_size, hipStream_t stream) {
  const float* x = (const float*)d_in[0];
  const float* wq = (const float*)d_in[1];
  const float* bq = (const float*)d_in[2];
  const float* wk = (const float*)d_in[3];
  const float* bk = (const float*)d_in[4];
  const float* wv = (const float*)d_in[5];
  const float* bv = (const float*)d_in[6];
  const float* wo = (const float*)d_in[7];
  const float* bo = (const float*)d_in[8];

  const int Bz = 2, S = 2048, D = 1024, H = 16;
  const size_t MS = (size_t)Bz * S;  // 4096 rows

  float* out = (float*)d_out;  // [2,2048,1024]
  float* wts = out + MS * D;   // [2,16,2048,2048]

  // workspace layout (u16 elems)
  u16* xb = (u16*)d_ws;                   // [4096,1024]        8 MB
  u16* wall = xb + MS * D;                // [4][1024,1024]^T   8 MB
  u16* qkv = wall + (size_t)4 * D * D;    // [4096,3072]       24 MB
  u16* Vt = qkv + MS * 3 * D;             // [2][1024,2048]     8 MB
  u16* Attb = Vt + (size_t)Bz * D * S;    // [4096,1024]        8 MB
  float* bqkv = (float*)(Attb + MS * D);  // [3072] f32        12 KB
  u16* Pb = (u16*)(bqkv + 3 * D);         // [2,16,2048,2048] 256 MB
  const size_t need_p =
      (size_t)((char*)Pb - (char*)d_ws) + MS * (size_t)H * S * 2 * 2;
  const bool use_p = ws_size >= need_p;

  dim3 blk(256);

  // ---- dtype prep ----
  cvt_x_kernel<<<1024, blk, 0, stream>>>(x, xb, (int)(MS * D / 4));
  wtrans_kernel<<<dim3(32, 32), blk, 0, stream>>>(wq, wall);
  wtrans_kernel<<<dim3(32, 32), blk, 0, stream>>>(wk, wall + (size_t)D * D);
  wtrans_kernel<<<dim3(32, 32), blk, 0, stream>>>(wv, wall + (size_t)2 * D * D);
  wtrans_kernel<<<dim3(32, 32), blk, 0, stream>>>(wo, wall + (size_t)3 * D * D);
  pack_bias_kernel<<<3, dim3(1024), 0, stream>>>(bq, bk, bv, bqkv);

  // ---- fused QKV projection: [4096,3072] = xb @ wqkv^T + bqkv -> bf16 ----
  dim3 gproj(3 * D / 128, (int)(MS / 64), 1);  // 24 x 64
  mm_nt<64, 128, 32, 64, false, true><<<gproj, blk, 0, stream>>>(
      xb, wall, bqkv, qkv, D, D, D, 3 * D, 0, 0, 0, 0, 0, 0, 1, 1.f);

  // ---- V^T per batch ----
  vtrans_kernel<<<dim3(32, 64, 2), blk, 0, stream>>>(qkv + 2 * D, Vt, 3 * D);

  // ---- fused scores + softmax -> wts fp32 (+ Pb bf16) ----
  if (use_p)
    score_softmax_kernel<true><<<2048, dim3(1024), 0, stream>>>(qkv, wts, Pb);
  else
    score_softmax_kernel<false><<<2048, dim3(1024), 0, stream>>>(qkv, wts, Pb);

  // ---- attended_h = P_h @ V_h -> Attb bf16 ----
  dim3 gav(1, S / 64, Bz * H);
  if (use_p)
    mm_nt<64, 64, 32, 32, false, true><<<gav, blk, 0, stream>>>(
        Pb, Vt, nullptr, Attb, S, S, S, D, (size_t)H * S * S, (size_t)S * S,
        (size_t)D * S, (size_t)64 * S, (size_t)S * D, 64, H, 1.f);
  else
    mm_nt<64, 64, 32, 32, true, true><<<gav, blk, 0, stream>>>(
        wts, Vt, nullptr, Attb, S, S, S, D, (size_t)H * S * S, (size_t)S * S,
        (size_t)D * S, (size_t)64 * S, (size_t)S * D, 64, H, 1.f);

  // ---- out = Attb @ wo^T + bo -> fp32 ----
  dim3 gout(D / 128, (int)(MS / 64), 1);
  mm_nt<64, 128, 32, 64, false, false><<<gout, blk, 0, stream>>>(
      Attb, wall + (size_t)3 * D * D, bo, out, D, D, D, D, 0, 0, 0, 0, 0, 0, 1,
      1.f);
}